// Round 2
// baseline (498.038 us; speedup 1.0000x reference)
//
#include <hip/hip_runtime.h>

// Problem constants (GNNNet_678604833376): B=2, N=50000, D=128, E=640000
// All float tensors are fp32 (reference dtype); intermediates kept bf16 for BW.
#define NNODES 50000
#define NBATCH 2
#define DIM    128
#define NEDGE  640000
#define M_TOT  (NBATCH*NNODES)   // 100000 rows for the GEMM

typedef unsigned short u16;
typedef unsigned int   u32;

typedef __attribute__((ext_vector_type(8))) short bf16x8;   // 8 bf16 = 4 VGPRs
typedef __attribute__((ext_vector_type(4))) float f32x4;

__device__ __forceinline__ float bf2f(u16 u){ return __uint_as_float(((u32)u)<<16); }
__device__ __forceinline__ u16 f2bf(float f){
    u32 x = __float_as_uint(f);
    x += 0x7fffu + ((x>>16)&1u);   // round-to-nearest-even
    return (u16)(x>>16);
}

// ---------- tiny prep kernels ----------

__global__ __launch_bounds__(256) void init_k(float* deg, int* cnt, int* fill){
    int i = blockIdx.x*256 + threadIdx.x;
    if (i < NNODES){ deg[i] = 1.0f; cnt[i] = 0; fill[i] = 0; }   // self-loop weight 1
}

__global__ __launch_bounds__(256) void count_k(const int* __restrict__ ei,
                                               const float* __restrict__ ea,
                                               float* deg, int* cnt){
    int e = blockIdx.x*256 + threadIdx.x;
    if (e < NEDGE){
        int c = ei[NEDGE + e];
        atomicAdd(&deg[c], ea[e]);
        atomicAdd(&cnt[c], 1);
    }
}

__global__ __launch_bounds__(256) void dinv_k(const float* deg, float* dinv){
    int i = blockIdx.x*256 + threadIdx.x;
    if (i < NNODES){ float d = deg[i]; dinv[i] = (d > 0.f) ? rsqrtf(d) : 0.f; }
}

// exclusive scan of cnt -> colstart (3 kernels, N=50000 -> 196 blocks <= 256)
__global__ __launch_bounds__(256) void scan1(const int* __restrict__ cnt,
                                             int* colstart, int* bsum){
    __shared__ int s[256];
    int tid = threadIdx.x;
    int i = blockIdx.x*256 + tid;
    int v = (i < NNODES) ? cnt[i] : 0;
    s[tid] = v; __syncthreads();
    #pragma unroll
    for (int off = 1; off < 256; off <<= 1){
        int t = (tid >= off) ? s[tid-off] : 0;
        __syncthreads();
        s[tid] += t;
        __syncthreads();
    }
    if (i < NNODES) colstart[i] = s[tid] - v;     // exclusive
    if (tid == 255) bsum[blockIdx.x] = s[255];
}

__global__ __launch_bounds__(256) void scan2(int* bsum, int nb){
    __shared__ int s[256];
    int tid = threadIdx.x;
    int v = (tid < nb) ? bsum[tid] : 0;
    s[tid] = v; __syncthreads();
    #pragma unroll
    for (int off = 1; off < 256; off <<= 1){
        int t = (tid >= off) ? s[tid-off] : 0;
        __syncthreads();
        s[tid] += t;
        __syncthreads();
    }
    if (tid < nb) bsum[tid] = s[tid] - v;         // exclusive
}

__global__ __launch_bounds__(256) void scan3(int* colstart, const int* bsum){
    int i = blockIdx.x*256 + threadIdx.x;
    if (i < NNODES) colstart[i] += bsum[i >> 8];
}

__global__ __launch_bounds__(256) void fill_k(const int* __restrict__ ei,
                                              const float* __restrict__ ea,
                                              const float* __restrict__ dinv,
                                              const int* __restrict__ colstart,
                                              int* fill, int* erow, float* enorm){
    int e = blockIdx.x*256 + threadIdx.x;
    if (e < NEDGE){
        int r = ei[e], c = ei[NEDGE + e];
        int pos = colstart[c] + atomicAdd(&fill[c], 1);
        erow[pos]  = r;
        enorm[pos] = dinv[r] * ea[e] * dinv[c];
    }
}

// transpose W (fp32) -> Wt (bf16), Wt[n][k] = W[k][n]
__global__ __launch_bounds__(256) void transposeW(const float* __restrict__ W, u16* __restrict__ Wt){
    int i = blockIdx.x*256 + threadIdx.x;   // 64 blocks x 256 = 16384
    int k = i >> 7, n = i & 127;
    Wt[n*DIM + k] = f2bf(W[i]);
}

// ---------- GEMM: H[M,128](bf16) = A[M,128](fp32->bf16) @ W[128,128] ----------
// Wt is pre-transposed bf16. Block = 256 thr = 4 waves; wave does 64 rows.
__global__ __launch_bounds__(256) void gemm128(const float* __restrict__ A,
                                               const u16* __restrict__ Wt,
                                               u16* __restrict__ H, int M){
    __shared__ u16 Wl[128][136];   // +8 pad; 272B row stride is 16B-aligned
    int tid = threadIdx.x;
    {
        const uint4* src = (const uint4*)Wt;   // 2048 x 16B
        #pragma unroll
        for (int j = 0; j < 8; ++j){
            int g = tid + j*256;
            int n = g >> 4;
            int k = (g & 15) * 8;
            *(uint4*)&Wl[n][k] = src[g];
        }
    }
    __syncthreads();

    int wave = tid >> 6, lane = tid & 63;
    int quad = lane >> 4, r = lane & 15;
    int row0 = blockIdx.x*256 + wave*64;

    f32x4 acc[4][8];
    #pragma unroll
    for (int mt = 0; mt < 4; ++mt)
        #pragma unroll
        for (int nt = 0; nt < 8; ++nt)
            acc[mt][nt] = (f32x4){0.f,0.f,0.f,0.f};

    #pragma unroll
    for (int ks = 0; ks < 4; ++ks){
        bf16x8 af[4];
        #pragma unroll
        for (int mt = 0; mt < 4; ++mt){
            int row = row0 + mt*16 + r;
            if (row < M){
                const float4* ap = (const float4*)&A[(size_t)row*DIM + ks*32 + quad*8];
                float4 lo = ap[0], hi = ap[1];
                af[mt][0] = (short)f2bf(lo.x); af[mt][1] = (short)f2bf(lo.y);
                af[mt][2] = (short)f2bf(lo.z); af[mt][3] = (short)f2bf(lo.w);
                af[mt][4] = (short)f2bf(hi.x); af[mt][5] = (short)f2bf(hi.y);
                af[mt][6] = (short)f2bf(hi.z); af[mt][7] = (short)f2bf(hi.w);
            } else {
                af[mt] = (bf16x8){0,0,0,0,0,0,0,0};
            }
        }
        #pragma unroll
        for (int nt = 0; nt < 8; ++nt){
            bf16x8 bfr = *(const bf16x8*)&Wl[nt*16 + r][ks*32 + quad*8];
            #pragma unroll
            for (int mt = 0; mt < 4; ++mt)
                acc[mt][nt] = __builtin_amdgcn_mfma_f32_16x16x32_bf16(af[mt], bfr, acc[mt][nt], 0, 0, 0);
        }
    }

    // C/D layout: col = lane&15 (=r), row = quad*4 + reg
    #pragma unroll
    for (int mt = 0; mt < 4; ++mt){
        #pragma unroll
        for (int reg = 0; reg < 4; ++reg){
            int row = row0 + mt*16 + quad*4 + reg;
            if (row < M){
                #pragma unroll
                for (int nt = 0; nt < 8; ++nt)
                    H[(size_t)row*DIM + nt*16 + r] = f2bf(acc[mt][nt][reg]);
            }
        }
    }
}

// ---------- gather-aggregate ----------
// out[b,n,:] = relu(bias + dinv[n]^2*h[b,n,:] + sum_e norm_e*h[b,row_e,:])
// OUT_F32=false -> packed bf16 (u32/lane); true -> float2/lane to d_out
template <bool OUT_F32>
__global__ __launch_bounds__(256) void gather_k(const u16* __restrict__ H,
                                                const int* __restrict__ erow,
                                                const float* __restrict__ enorm,
                                                const int* __restrict__ colstart,
                                                const int* __restrict__ cnt,
                                                const float* __restrict__ dinv,
                                                const float* __restrict__ bias,
                                                void* __restrict__ out){
    int wave = threadIdx.x >> 6, lane = threadIdx.x & 63;
    int n = blockIdx.x*4 + wave;
    if (n >= NNODES) return;
    int b = blockIdx.y;
    const u32* Hb = (const u32*)(H + (size_t)b*NNODES*DIM);

    float dn = dinv[n];
    u32 sv = Hb[(size_t)n*64 + lane];
    float a0 = dn*dn*bf2f((u16)(sv & 0xffff));
    float a1 = dn*dn*bf2f((u16)(sv >> 16));

    int s = colstart[n], c = cnt[n];
    for (int j = 0; j < c; ++j){
        int rsrc = erow[s + j];
        float w  = enorm[s + j];
        u32 hv = Hb[(size_t)rsrc*64 + lane];
        a0 = fmaf(w, bf2f((u16)(hv & 0xffff)), a0);
        a1 = fmaf(w, bf2f((u16)(hv >> 16)), a1);
    }
    a0 = fmaxf(a0 + bias[lane*2    ], 0.f);
    a1 = fmaxf(a1 + bias[lane*2 + 1], 0.f);
    if (OUT_F32){
        float2* Ob = (float2*)((float*)out + (size_t)b*NNODES*DIM);
        Ob[(size_t)n*64 + lane] = make_float2(a0, a1);
    } else {
        u32* Ob = (u32*)((u16*)out + (size_t)b*NNODES*DIM);
        Ob[(size_t)n*64 + lane] = (u32)f2bf(a0) | ((u32)f2bf(a1) << 16);
    }
}

// ---------- launch ----------
extern "C" void kernel_launch(void* const* d_in, const int* in_sizes, int n_in,
                              void* d_out, int out_size, void* d_ws, size_t ws_size,
                              hipStream_t stream){
    const float* x  = (const float*)d_in[0];
    const int*   ei = (const int*)  d_in[1];
    const float* ea = (const float*)d_in[2];
    const float* W1 = (const float*)d_in[3];
    const float* b1 = (const float*)d_in[4];
    const float* W2 = (const float*)d_in[5];
    const float* b2 = (const float*)d_in[6];

    char* p = (char*)d_ws;
    auto alloc = [&](size_t bytes)->char*{ char* r = p; p += (bytes + 511) & ~(size_t)511; return r; };
    float* deg      = (float*)alloc(NNODES*4);
    float* dinv     = (float*)alloc(NNODES*4);
    int*   cnt      = (int*)  alloc(NNODES*4);
    int*   colstart = (int*)  alloc(NNODES*4);
    int*   fill     = (int*)  alloc(NNODES*4);
    int*   bsum     = (int*)  alloc(1024);
    int*   erow     = (int*)  alloc((size_t)NEDGE*4);
    float* enorm    = (float*)alloc((size_t)NEDGE*4);
    u16*   Wt1      = (u16*)  alloc(DIM*DIM*2);
    u16*   Wt2      = (u16*)  alloc(DIM*DIM*2);
    u16*   h        = (u16*)  alloc((size_t)M_TOT*DIM*2);   // bf16 intermediates
    u16*   o1f      = (u16*)  alloc((size_t)M_TOT*DIM*2);   // bf16, but gemm reads fp32...
    // o1 must be fp32 for gemm128's A input -> allocate fp32 buffer instead
    float* o1       = (float*)alloc((size_t)M_TOT*DIM*4);
    (void)o1f;

    const int NBL_N = (NNODES + 255)/256;   // 196
    const int NBL_E = (NEDGE  + 255)/256;
    const int NTILE = (M_TOT + 255)/256;    // 391

    transposeW<<<64, 256, 0, stream>>>(W1, Wt1);
    transposeW<<<64, 256, 0, stream>>>(W2, Wt2);
    init_k <<<NBL_N, 256, 0, stream>>>(deg, cnt, fill);
    count_k<<<NBL_E, 256, 0, stream>>>(ei, ea, deg, cnt);
    dinv_k <<<NBL_N, 256, 0, stream>>>(deg, dinv);
    scan1  <<<NBL_N, 256, 0, stream>>>(cnt, colstart, bsum);
    scan2  <<<1,     256, 0, stream>>>(bsum, NBL_N);
    scan3  <<<NBL_N, 256, 0, stream>>>(colstart, bsum);
    fill_k <<<NBL_E, 256, 0, stream>>>(ei, ea, dinv, colstart, fill, erow, enorm);

    dim3 gg((NNODES + 3)/4, NBATCH);
    gemm128 <<<NTILE, 256, 0, stream>>>(x, Wt1, h, M_TOT);
    gather_k<true><<<gg, 256, 0, stream>>>(h, erow, enorm, colstart, cnt, dinv, b1, o1);
    gemm128 <<<NTILE, 256, 0, stream>>>(o1, Wt2, h, M_TOT);
    gather_k<true><<<gg, 256, 0, stream>>>(h, erow, enorm, colstart, cnt, dinv, b2, d_out);
}

// Round 3
// 331.898 us; speedup vs baseline: 1.5006x; 1.5006x over previous
//
#include <hip/hip_runtime.h>

// Problem constants (GNNNet_678604833376): B=2, N=50000, D=128, E=640000
#define NNODES 50000
#define NBATCH 2
#define DIM    128
#define NEDGE  640000
#define M_TOT  (NBATCH*NNODES)   // 100000 rows for the GEMM

typedef unsigned short u16;
typedef unsigned int   u32;

typedef __attribute__((ext_vector_type(8))) short bf16x8;   // 8 bf16 = 4 VGPRs
typedef __attribute__((ext_vector_type(4))) float f32x4;

__device__ __forceinline__ float bf2f(u16 u){ return __uint_as_float(((u32)u)<<16); }
__device__ __forceinline__ u16 f2bf(float f){
    u32 x = __float_as_uint(f);
    x += 0x7fffu + ((x>>16)&1u);   // round-to-nearest-even
    return (u16)(x>>16);
}

// ---------- tiny prep kernels ----------

__global__ __launch_bounds__(256) void init_k(float* deg, int* cnt, int* fill){
    int i = blockIdx.x*256 + threadIdx.x;
    if (i < NNODES){ deg[i] = 1.0f; cnt[i] = 0; fill[i] = 0; }   // self-loop weight 1
}

__global__ __launch_bounds__(256) void count_k(const int* __restrict__ ei,
                                               const float* __restrict__ ea,
                                               float* deg, int* cnt){
    int e = blockIdx.x*256 + threadIdx.x;
    if (e < NEDGE){
        int c = ei[NEDGE + e];
        atomicAdd(&deg[c], ea[e]);
        atomicAdd(&cnt[c], 1);
    }
}

// exclusive scan of cnt -> colstart; also computes dinv = rsqrt(deg) (fused)
__global__ __launch_bounds__(256) void scan1(const int* __restrict__ cnt,
                                             int* colstart, int* bsum,
                                             const float* __restrict__ deg,
                                             float* __restrict__ dinv){
    __shared__ int s[256];
    int tid = threadIdx.x;
    int i = blockIdx.x*256 + tid;
    if (i < NNODES){ float d = deg[i]; dinv[i] = (d > 0.f) ? rsqrtf(d) : 0.f; }
    int v = (i < NNODES) ? cnt[i] : 0;
    s[tid] = v; __syncthreads();
    #pragma unroll
    for (int off = 1; off < 256; off <<= 1){
        int t = (tid >= off) ? s[tid-off] : 0;
        __syncthreads();
        s[tid] += t;
        __syncthreads();
    }
    if (i < NNODES) colstart[i] = s[tid] - v;     // exclusive
    if (tid == 255) bsum[blockIdx.x] = s[255];
}

__global__ __launch_bounds__(256) void scan2(int* bsum, int nb){
    __shared__ int s[256];
    int tid = threadIdx.x;
    int v = (tid < nb) ? bsum[tid] : 0;
    s[tid] = v; __syncthreads();
    #pragma unroll
    for (int off = 1; off < 256; off <<= 1){
        int t = (tid >= off) ? s[tid-off] : 0;
        __syncthreads();
        s[tid] += t;
        __syncthreads();
    }
    if (tid < nb) bsum[tid] = s[tid] - v;         // exclusive
}

__global__ __launch_bounds__(256) void scan3(int* colstart, const int* bsum){
    int i = blockIdx.x*256 + threadIdx.x;
    if (i < NNODES) colstart[i] += bsum[i >> 8];
}

// CSR bucket fill: epack[pos] = {src_row, norm}
__global__ __launch_bounds__(256) void fill_k(const int* __restrict__ ei,
                                              const float* __restrict__ ea,
                                              const float* __restrict__ dinv,
                                              const int* __restrict__ colstart,
                                              int* fill, int2* __restrict__ epack){
    int e = blockIdx.x*256 + threadIdx.x;
    if (e < NEDGE){
        int r = ei[e], c = ei[NEDGE + e];
        int pos = colstart[c] + atomicAdd(&fill[c], 1);
        epack[pos] = make_int2(r, __float_as_int(dinv[r] * ea[e] * dinv[c]));
    }
}

// transpose both W (fp32) -> Wt (bf16), Wt[n][k] = W[k][n]. 128 blocks.
__global__ __launch_bounds__(256) void transposeW(const float* __restrict__ W1, u16* __restrict__ Wt1,
                                                  const float* __restrict__ W2, u16* __restrict__ Wt2){
    int i = blockIdx.x*256 + threadIdx.x;
    const float* W = (i < 16384) ? W1 : W2;
    u16* Wt       = (i < 16384) ? Wt1 : Wt2;
    int ii = i & 16383;
    int k = ii >> 7, n = ii & 127;
    Wt[n*DIM + k] = f2bf(W[ii]);
}

// ---------- GEMM: H[M,128](bf16) = A[M,128](AT->bf16) @ W[128,128] ----------
// AT = float (layer 1 input x) or u16 (bf16 activations). Wt pre-transposed bf16.
__device__ __forceinline__ bf16x8 load_frag(const float* A, size_t off){
    const float4* ap = (const float4*)(A + off);
    float4 lo = ap[0], hi = ap[1];
    bf16x8 r;
    r[0] = (short)f2bf(lo.x); r[1] = (short)f2bf(lo.y);
    r[2] = (short)f2bf(lo.z); r[3] = (short)f2bf(lo.w);
    r[4] = (short)f2bf(hi.x); r[5] = (short)f2bf(hi.y);
    r[6] = (short)f2bf(hi.z); r[7] = (short)f2bf(hi.w);
    return r;
}
__device__ __forceinline__ bf16x8 load_frag(const u16* A, size_t off){
    return *(const bf16x8*)(A + off);
}

template <typename AT>
__global__ __launch_bounds__(256) void gemm128(const AT* __restrict__ A,
                                               const u16* __restrict__ Wt,
                                               u16* __restrict__ H, int M){
    __shared__ u16 Wl[128][136];   // +8 pad keeps 16B alignment, breaks 128-stride
    int tid = threadIdx.x;
    {
        const uint4* src = (const uint4*)Wt;   // 2048 x 16B
        #pragma unroll
        for (int j = 0; j < 8; ++j){
            int g = tid + j*256;
            int n = g >> 4;
            int k = (g & 15) * 8;
            *(uint4*)&Wl[n][k] = src[g];
        }
    }
    __syncthreads();

    int wave = tid >> 6, lane = tid & 63;
    int quad = lane >> 4, r = lane & 15;
    int row0 = blockIdx.x*256 + wave*64;

    f32x4 acc[4][8];
    #pragma unroll
    for (int mt = 0; mt < 4; ++mt)
        #pragma unroll
        for (int nt = 0; nt < 8; ++nt)
            acc[mt][nt] = (f32x4){0.f,0.f,0.f,0.f};

    #pragma unroll
    for (int ks = 0; ks < 4; ++ks){
        bf16x8 af[4];
        #pragma unroll
        for (int mt = 0; mt < 4; ++mt){
            int row = row0 + mt*16 + r;
            if (row < M)
                af[mt] = load_frag(A, (size_t)row*DIM + ks*32 + quad*8);
            else
                af[mt] = (bf16x8){0,0,0,0,0,0,0,0};
        }
        #pragma unroll
        for (int nt = 0; nt < 8; ++nt){
            bf16x8 bfr = *(const bf16x8*)&Wl[nt*16 + r][ks*32 + quad*8];
            #pragma unroll
            for (int mt = 0; mt < 4; ++mt)
                acc[mt][nt] = __builtin_amdgcn_mfma_f32_16x16x32_bf16(af[mt], bfr, acc[mt][nt], 0, 0, 0);
        }
    }

    // C/D layout: col = lane&15 (=r), row = quad*4 + reg
    #pragma unroll
    for (int mt = 0; mt < 4; ++mt){
        #pragma unroll
        for (int reg = 0; reg < 4; ++reg){
            int row = row0 + mt*16 + quad*4 + reg;
            if (row < M){
                #pragma unroll
                for (int nt = 0; nt < 8; ++nt)
                    H[(size_t)row*DIM + nt*16 + r] = f2bf(acc[mt][nt][reg]);
            }
        }
    }
}

// ---------- gather-aggregate, both batches per wave ----------
// out[b,n,:] = relu(bias + dinv[n]^2*h[b,n,:] + sum_e norm_e*h[b,row_e,:])
// Lane-parallel edge-metadata load + shfl broadcast; j-loop unrolled x4
// -> 8 independent 256B row-loads in flight per wave (2 batches x 4 edges).
#define EDGE_FMA(W_, V0_, V1_)                                            \
    a0 = fmaf(W_, bf2f((u16)((V0_) & 0xffff)), a0);                       \
    a1 = fmaf(W_, bf2f((u16)((V0_) >> 16)),    a1);                       \
    a2 = fmaf(W_, bf2f((u16)((V1_) & 0xffff)), a2);                       \
    a3 = fmaf(W_, bf2f((u16)((V1_) >> 16)),    a3);

template <bool OUT_F32>
__global__ __launch_bounds__(256) void gather2_k(const u16* __restrict__ H,
                                                 const int2* __restrict__ epack,
                                                 const int* __restrict__ colstart,
                                                 const int* __restrict__ cnt,
                                                 const float* __restrict__ dinv,
                                                 const float* __restrict__ bias,
                                                 void* __restrict__ out){
    int wave = threadIdx.x >> 6, lane = threadIdx.x & 63;
    int n = blockIdx.x*4 + wave;
    if (n >= NNODES) return;
    const u32* H0 = (const u32*)H;                 // batch 0, 64 u32 per row
    const u32* H1 = H0 + (size_t)NNODES*64;        // batch 1

    float dn = dinv[n], dn2 = dn*dn;
    u32 sv0 = H0[(size_t)n*64 + lane];
    u32 sv1 = H1[(size_t)n*64 + lane];
    float a0 = dn2*bf2f((u16)(sv0 & 0xffff)), a1 = dn2*bf2f((u16)(sv0 >> 16));
    float a2 = dn2*bf2f((u16)(sv1 & 0xffff)), a3 = dn2*bf2f((u16)(sv1 >> 16));

    int s = colstart[n], c = cnt[n];
    for (int base = 0; base < c; base += 64){
        int m = min(64, c - base);
        int2 ep = make_int2(0, 0);
        if (lane < m) ep = epack[s + base + lane];
        int j = 0;
        for (; j + 4 <= m; j += 4){
            int   r0 = __shfl(ep.x, j+0), r1 = __shfl(ep.x, j+1);
            int   r2 = __shfl(ep.x, j+2), r3 = __shfl(ep.x, j+3);
            float w0 = __int_as_float(__shfl(ep.y, j+0));
            float w1 = __int_as_float(__shfl(ep.y, j+1));
            float w2 = __int_as_float(__shfl(ep.y, j+2));
            float w3 = __int_as_float(__shfl(ep.y, j+3));
            u32 v00 = H0[(size_t)r0*64 + lane], v10 = H1[(size_t)r0*64 + lane];
            u32 v01 = H0[(size_t)r1*64 + lane], v11 = H1[(size_t)r1*64 + lane];
            u32 v02 = H0[(size_t)r2*64 + lane], v12 = H1[(size_t)r2*64 + lane];
            u32 v03 = H0[(size_t)r3*64 + lane], v13 = H1[(size_t)r3*64 + lane];
            EDGE_FMA(w0, v00, v10)
            EDGE_FMA(w1, v01, v11)
            EDGE_FMA(w2, v02, v12)
            EDGE_FMA(w3, v03, v13)
        }
        for (; j < m; ++j){
            int   rr = __shfl(ep.x, j);
            float ww = __int_as_float(__shfl(ep.y, j));
            u32 v0 = H0[(size_t)rr*64 + lane], v1 = H1[(size_t)rr*64 + lane];
            EDGE_FMA(ww, v0, v1)
        }
    }
    float bb0 = bias[lane*2], bb1 = bias[lane*2 + 1];
    a0 = fmaxf(a0 + bb0, 0.f); a1 = fmaxf(a1 + bb1, 0.f);
    a2 = fmaxf(a2 + bb0, 0.f); a3 = fmaxf(a3 + bb1, 0.f);
    if (OUT_F32){
        float2* O = (float2*)out;
        O[(size_t)n*64 + lane]            = make_float2(a0, a1);
        O[(size_t)(NNODES + n)*64 + lane] = make_float2(a2, a3);
    } else {
        u32* O = (u32*)out;
        O[(size_t)n*64 + lane]            = (u32)f2bf(a0) | ((u32)f2bf(a1) << 16);
        O[(size_t)(NNODES + n)*64 + lane] = (u32)f2bf(a2) | ((u32)f2bf(a3) << 16);
    }
}

// ---------- launch ----------
extern "C" void kernel_launch(void* const* d_in, const int* in_sizes, int n_in,
                              void* d_out, int out_size, void* d_ws, size_t ws_size,
                              hipStream_t stream){
    const float* x  = (const float*)d_in[0];
    const int*   ei = (const int*)  d_in[1];
    const float* ea = (const float*)d_in[2];
    const float* W1 = (const float*)d_in[3];
    const float* b1 = (const float*)d_in[4];
    const float* W2 = (const float*)d_in[5];
    const float* b2 = (const float*)d_in[6];

    char* p = (char*)d_ws;
    auto alloc = [&](size_t bytes)->char*{ char* r = p; p += (bytes + 511) & ~(size_t)511; return r; };
    float* deg      = (float*)alloc(NNODES*4);
    float* dinv     = (float*)alloc(NNODES*4);
    int*   cnt      = (int*)  alloc(NNODES*4);
    int*   colstart = (int*)  alloc(NNODES*4);
    int*   fill     = (int*)  alloc(NNODES*4);
    int*   bsum     = (int*)  alloc(1024);
    int2*  epack    = (int2*) alloc((size_t)NEDGE*8);
    u16*   Wt1      = (u16*)  alloc(DIM*DIM*2);
    u16*   Wt2      = (u16*)  alloc(DIM*DIM*2);
    u16*   h        = (u16*)  alloc((size_t)M_TOT*DIM*2);   // bf16 intermediates
    u16*   o1       = (u16*)  alloc((size_t)M_TOT*DIM*2);   // bf16 activations

    const int NBL_N = (NNODES + 255)/256;   // 196
    const int NBL_E = (NEDGE  + 255)/256;
    const int NTILE = (M_TOT + 255)/256;    // 391
    const int NBL_G = (NNODES + 3)/4;       // 12500

    transposeW<<<128, 256, 0, stream>>>(W1, Wt1, W2, Wt2);
    init_k <<<NBL_N, 256, 0, stream>>>(deg, cnt, fill);
    count_k<<<NBL_E, 256, 0, stream>>>(ei, ea, deg, cnt);
    scan1  <<<NBL_N, 256, 0, stream>>>(cnt, colstart, bsum, deg, dinv);
    scan2  <<<1,     256, 0, stream>>>(bsum, NBL_N);
    scan3  <<<NBL_N, 256, 0, stream>>>(colstart, bsum);
    fill_k <<<NBL_E, 256, 0, stream>>>(ei, ea, dinv, colstart, fill, epack);

    gemm128<float><<<NTILE, 256, 0, stream>>>(x, Wt1, h, M_TOT);
    gather2_k<false><<<NBL_G, 256, 0, stream>>>(h, epack, colstart, cnt, dinv, b1, o1);
    gemm128<u16>  <<<NTILE, 256, 0, stream>>>(o1, Wt2, h, M_TOT);
    gather2_k<true> <<<NBL_G, 256, 0, stream>>>(h, epack, colstart, cnt, dinv, b2, d_out);
}

// Round 4
// 286.289 us; speedup vs baseline: 1.7396x; 1.1593x over previous
//
#include <hip/hip_runtime.h>

// Problem constants (GNNNet_678604833376): B=2, N=50000, D=128, E=640000
#define NNODES 50000
#define NBATCH 2
#define DIM    128
#define NEDGE  640000
#define M_TOT  (NBATCH*NNODES)   // 100000 rows for the GEMM
#define NXCD   8

typedef unsigned short u16;
typedef unsigned int   u32;
typedef unsigned long long u64;

typedef __attribute__((ext_vector_type(8))) short bf16x8;   // 8 bf16 = 4 VGPRs
typedef __attribute__((ext_vector_type(4))) float f32x4;

__device__ __forceinline__ float bf2f(u16 u){ return __uint_as_float(((u32)u)<<16); }
__device__ __forceinline__ u16 f2bf(float f){
    u32 x = __float_as_uint(f);
    x += 0x7fffu + ((x>>16)&1u);   // round-to-nearest-even
    return (u16)(x>>16);
}

// ---------- histogram: per-XCD partials, L2-resident workgroup-scope atomics ----------
// part[xcc][c] accumulates (fixed24(ea) << 32) | 1.  All updates to partition
// xcc come from waves physically on XCD xcc (s_getreg HW_REG_XCC_ID), so the
// atomic RMW at that XCD's L2 is sufficient — no memory-side 64B RMW per edge.
// Returned old value = this edge's rank in its (partition, column) bucket.
__global__ __launch_bounds__(256) void count_k(const int* __restrict__ ei,
                                               const float* __restrict__ ea,
                                               u64* __restrict__ part,
                                               u32* __restrict__ rankpack){
    // simm16 = ID(20=HW_REG_XCC_ID) | offset(0)<<6 | (size(4)-1)<<11
    u32 xcc = __builtin_amdgcn_s_getreg(6164) & 7u;
    int e = blockIdx.x*256 + threadIdx.x;
    if (e < NEDGE){
        int c = ei[NEDGE + e];
        u64 inc = (((u64)__float2uint_rn(ea[e] * 16777216.0f)) << 32) | 1ull;
        u64 old = __hip_atomic_fetch_add(&part[(size_t)xcc*NNODES + c], inc,
                                         __ATOMIC_RELAXED, __HIP_MEMORY_SCOPE_WORKGROUP);
        rankpack[e] = ((u32)old & 0xffffu) | (xcc << 16);
    }
}

// ---------- fused reduce + block-scan ----------
// Per node: combine 8 partials -> cnt, per-partition offsets poff[p][n],
// deg = 1 + sum(ea), dinv = rsqrt(deg); then exclusive block scan of cnt.
__global__ __launch_bounds__(256) void scan1(const u64* __restrict__ part,
                                             int* __restrict__ cnt,
                                             int* __restrict__ poff,
                                             float* __restrict__ dinv,
                                             int* colstart, int* bsum){
    __shared__ int s[256];
    int tid = threadIdx.x;
    int n = blockIdx.x*256 + tid;
    int v = 0;
    if (n < NNODES){
        int run = 0; u64 fsum = 0;
        #pragma unroll
        for (int p = 0; p < NXCD; ++p){
            u64 pv = part[(size_t)p*NNODES + n];
            poff[p*NNODES + n] = run;
            run  += (int)(pv & 0xffffffffu);
            fsum += (pv >> 32);
        }
        cnt[n] = run;
        v = run;
        float deg = 1.0f + (float)fsum * (1.0f/16777216.0f);   // deg >= 1
        dinv[n] = rsqrtf(deg);
    }
    s[tid] = v; __syncthreads();
    #pragma unroll
    for (int off = 1; off < 256; off <<= 1){
        int t = (tid >= off) ? s[tid-off] : 0;
        __syncthreads();
        s[tid] += t;
        __syncthreads();
    }
    if (n < NNODES) colstart[n] = s[tid] - v;     // exclusive within block
    if (tid == 255) bsum[blockIdx.x] = s[255];
}

__global__ __launch_bounds__(256) void scan2(int* bsum, int nb){
    __shared__ int s[256];
    int tid = threadIdx.x;
    int v = (tid < nb) ? bsum[tid] : 0;
    s[tid] = v; __syncthreads();
    #pragma unroll
    for (int off = 1; off < 256; off <<= 1){
        int t = (tid >= off) ? s[tid-off] : 0;
        __syncthreads();
        s[tid] += t;
        __syncthreads();
    }
    if (tid < nb) bsum[tid] = s[tid] - v;         // exclusive
}

__global__ __launch_bounds__(256) void scan3(int* colstart, const int* bsum){
    int i = blockIdx.x*256 + threadIdx.x;
    if (i < NNODES) colstart[i] += bsum[i >> 8];
}

// ---------- CSR bucket fill (NO atomic: pos from colstart + poff + rank) ----------
__global__ __launch_bounds__(256) void fill_k(const int* __restrict__ ei,
                                              const float* __restrict__ ea,
                                              const float* __restrict__ dinv,
                                              const int* __restrict__ colstart,
                                              const int* __restrict__ poff,
                                              const u32* __restrict__ rankpack,
                                              int2* __restrict__ epack){
    int e = blockIdx.x*256 + threadIdx.x;
    if (e < NEDGE){
        int r = ei[e], c = ei[NEDGE + e];
        u32 rp = rankpack[e];
        int pos = colstart[c] + poff[(rp >> 16)*NNODES + c] + (int)(rp & 0xffffu);
        epack[pos] = make_int2(r, __float_as_int(dinv[r] * ea[e] * dinv[c]));
    }
}

// transpose both W (fp32) -> Wt (bf16), Wt[n][k] = W[k][n]. 128 blocks.
__global__ __launch_bounds__(256) void transposeW(const float* __restrict__ W1, u16* __restrict__ Wt1,
                                                  const float* __restrict__ W2, u16* __restrict__ Wt2){
    int i = blockIdx.x*256 + threadIdx.x;
    const float* W = (i < 16384) ? W1 : W2;
    u16* Wt       = (i < 16384) ? Wt1 : Wt2;
    int ii = i & 16383;
    int k = ii >> 7, n = ii & 127;
    Wt[n*DIM + k] = f2bf(W[ii]);
}

// ---------- GEMM: H[M,128](bf16) = A[M,128](AT->bf16) @ W[128,128] ----------
__device__ __forceinline__ bf16x8 load_frag(const float* A, size_t off){
    const float4* ap = (const float4*)(A + off);
    float4 lo = ap[0], hi = ap[1];
    bf16x8 r;
    r[0] = (short)f2bf(lo.x); r[1] = (short)f2bf(lo.y);
    r[2] = (short)f2bf(lo.z); r[3] = (short)f2bf(lo.w);
    r[4] = (short)f2bf(hi.x); r[5] = (short)f2bf(hi.y);
    r[6] = (short)f2bf(hi.z); r[7] = (short)f2bf(hi.w);
    return r;
}
__device__ __forceinline__ bf16x8 load_frag(const u16* A, size_t off){
    return *(const bf16x8*)(A + off);
}

template <typename AT>
__global__ __launch_bounds__(256) void gemm128(const AT* __restrict__ A,
                                               const u16* __restrict__ Wt,
                                               u16* __restrict__ H, int M){
    __shared__ u16 Wl[128][136];   // +8 pad keeps 16B alignment, breaks 128-stride
    int tid = threadIdx.x;
    {
        const uint4* src = (const uint4*)Wt;   // 2048 x 16B
        #pragma unroll
        for (int j = 0; j < 8; ++j){
            int g = tid + j*256;
            int n = g >> 4;
            int k = (g & 15) * 8;
            *(uint4*)&Wl[n][k] = src[g];
        }
    }
    __syncthreads();

    int wave = tid >> 6, lane = tid & 63;
    int quad = lane >> 4, r = lane & 15;
    int row0 = blockIdx.x*256 + wave*64;

    f32x4 acc[4][8];
    #pragma unroll
    for (int mt = 0; mt < 4; ++mt)
        #pragma unroll
        for (int nt = 0; nt < 8; ++nt)
            acc[mt][nt] = (f32x4){0.f,0.f,0.f,0.f};

    #pragma unroll
    for (int ks = 0; ks < 4; ++ks){
        bf16x8 af[4];
        #pragma unroll
        for (int mt = 0; mt < 4; ++mt){
            int row = row0 + mt*16 + r;
            if (row < M)
                af[mt] = load_frag(A, (size_t)row*DIM + ks*32 + quad*8);
            else
                af[mt] = (bf16x8){0,0,0,0,0,0,0,0};
        }
        #pragma unroll
        for (int nt = 0; nt < 8; ++nt){
            bf16x8 bfr = *(const bf16x8*)&Wl[nt*16 + r][ks*32 + quad*8];
            #pragma unroll
            for (int mt = 0; mt < 4; ++mt)
                acc[mt][nt] = __builtin_amdgcn_mfma_f32_16x16x32_bf16(af[mt], bfr, acc[mt][nt], 0, 0, 0);
        }
    }

    // C/D layout: col = lane&15 (=r), row = quad*4 + reg
    #pragma unroll
    for (int mt = 0; mt < 4; ++mt){
        #pragma unroll
        for (int reg = 0; reg < 4; ++reg){
            int row = row0 + mt*16 + quad*4 + reg;
            if (row < M){
                #pragma unroll
                for (int nt = 0; nt < 8; ++nt)
                    H[(size_t)row*DIM + nt*16 + r] = f2bf(acc[mt][nt][reg]);
            }
        }
    }
}

// ---------- gather-aggregate, both batches per wave ----------
#define EDGE_FMA(W_, V0_, V1_)                                            \
    a0 = fmaf(W_, bf2f((u16)((V0_) & 0xffff)), a0);                       \
    a1 = fmaf(W_, bf2f((u16)((V0_) >> 16)),    a1);                       \
    a2 = fmaf(W_, bf2f((u16)((V1_) & 0xffff)), a2);                       \
    a3 = fmaf(W_, bf2f((u16)((V1_) >> 16)),    a3);

template <bool OUT_F32>
__global__ __launch_bounds__(256) void gather2_k(const u16* __restrict__ H,
                                                 const int2* __restrict__ epack,
                                                 const int* __restrict__ colstart,
                                                 const int* __restrict__ cnt,
                                                 const float* __restrict__ dinv,
                                                 const float* __restrict__ bias,
                                                 void* __restrict__ out){
    int wave = threadIdx.x >> 6, lane = threadIdx.x & 63;
    int n = blockIdx.x*4 + wave;
    if (n >= NNODES) return;
    const u32* H0 = (const u32*)H;                 // batch 0, 64 u32 per row
    const u32* H1 = H0 + (size_t)NNODES*64;        // batch 1

    float dn = dinv[n], dn2 = dn*dn;
    u32 sv0 = H0[(size_t)n*64 + lane];
    u32 sv1 = H1[(size_t)n*64 + lane];
    float a0 = dn2*bf2f((u16)(sv0 & 0xffff)), a1 = dn2*bf2f((u16)(sv0 >> 16));
    float a2 = dn2*bf2f((u16)(sv1 & 0xffff)), a3 = dn2*bf2f((u16)(sv1 >> 16));

    int s = colstart[n], c = cnt[n];
    for (int base = 0; base < c; base += 64){
        int m = min(64, c - base);
        int2 ep = make_int2(0, 0);
        if (lane < m) ep = epack[s + base + lane];
        int j = 0;
        for (; j + 4 <= m; j += 4){
            int   r0 = __shfl(ep.x, j+0), r1 = __shfl(ep.x, j+1);
            int   r2 = __shfl(ep.x, j+2), r3 = __shfl(ep.x, j+3);
            float w0 = __int_as_float(__shfl(ep.y, j+0));
            float w1 = __int_as_float(__shfl(ep.y, j+1));
            float w2 = __int_as_float(__shfl(ep.y, j+2));
            float w3 = __int_as_float(__shfl(ep.y, j+3));
            u32 v00 = H0[(size_t)r0*64 + lane], v10 = H1[(size_t)r0*64 + lane];
            u32 v01 = H0[(size_t)r1*64 + lane], v11 = H1[(size_t)r1*64 + lane];
            u32 v02 = H0[(size_t)r2*64 + lane], v12 = H1[(size_t)r2*64 + lane];
            u32 v03 = H0[(size_t)r3*64 + lane], v13 = H1[(size_t)r3*64 + lane];
            EDGE_FMA(w0, v00, v10)
            EDGE_FMA(w1, v01, v11)
            EDGE_FMA(w2, v02, v12)
            EDGE_FMA(w3, v03, v13)
        }
        for (; j < m; ++j){
            int   rr = __shfl(ep.x, j);
            float ww = __int_as_float(__shfl(ep.y, j));
            u32 v0 = H0[(size_t)rr*64 + lane], v1 = H1[(size_t)rr*64 + lane];
            EDGE_FMA(ww, v0, v1)
        }
    }
    float bb0 = bias[lane*2], bb1 = bias[lane*2 + 1];
    a0 = fmaxf(a0 + bb0, 0.f); a1 = fmaxf(a1 + bb1, 0.f);
    a2 = fmaxf(a2 + bb0, 0.f); a3 = fmaxf(a3 + bb1, 0.f);
    if (OUT_F32){
        float2* O = (float2*)out;
        O[(size_t)n*64 + lane]            = make_float2(a0, a1);
        O[(size_t)(NNODES + n)*64 + lane] = make_float2(a2, a3);
    } else {
        u32* O = (u32*)out;
        O[(size_t)n*64 + lane]            = (u32)f2bf(a0) | ((u32)f2bf(a1) << 16);
        O[(size_t)(NNODES + n)*64 + lane] = (u32)f2bf(a2) | ((u32)f2bf(a3) << 16);
    }
}

// ---------- launch ----------
extern "C" void kernel_launch(void* const* d_in, const int* in_sizes, int n_in,
                              void* d_out, int out_size, void* d_ws, size_t ws_size,
                              hipStream_t stream){
    const float* x  = (const float*)d_in[0];
    const int*   ei = (const int*)  d_in[1];
    const float* ea = (const float*)d_in[2];
    const float* W1 = (const float*)d_in[3];
    const float* b1 = (const float*)d_in[4];
    const float* W2 = (const float*)d_in[5];
    const float* b2 = (const float*)d_in[6];

    char* p = (char*)d_ws;
    auto alloc = [&](size_t bytes)->char*{ char* r = p; p += (bytes + 511) & ~(size_t)511; return r; };
    u64*   part     = (u64*)  alloc((size_t)NXCD*NNODES*8);   // 3.2 MB partial histograms
    u32*   rankpack = (u32*)  alloc((size_t)NEDGE*4);
    int*   poff     = (int*)  alloc((size_t)NXCD*NNODES*4);
    float* dinv     = (float*)alloc(NNODES*4);
    int*   cnt      = (int*)  alloc(NNODES*4);
    int*   colstart = (int*)  alloc(NNODES*4);
    int*   bsum     = (int*)  alloc(1024);
    int2*  epack    = (int2*) alloc((size_t)NEDGE*8);
    u16*   Wt1      = (u16*)  alloc(DIM*DIM*2);
    u16*   Wt2      = (u16*)  alloc(DIM*DIM*2);
    u16*   h        = (u16*)  alloc((size_t)M_TOT*DIM*2);   // bf16 intermediates
    u16*   o1       = (u16*)  alloc((size_t)M_TOT*DIM*2);   // bf16 activations

    const int NBL_N = (NNODES + 255)/256;   // 196
    const int NBL_E = (NEDGE  + 255)/256;
    const int NTILE = (M_TOT + 255)/256;    // 391
    const int NBL_G = (NNODES + 3)/4;       // 12500

    hipMemsetAsync(part, 0, (size_t)NXCD*NNODES*8, stream);
    transposeW<<<128, 256, 0, stream>>>(W1, Wt1, W2, Wt2);
    count_k<<<NBL_E, 256, 0, stream>>>(ei, ea, part, rankpack);
    scan1  <<<NBL_N, 256, 0, stream>>>(part, cnt, poff, dinv, colstart, bsum);
    scan2  <<<1,     256, 0, stream>>>(bsum, NBL_N);
    scan3  <<<NBL_N, 256, 0, stream>>>(colstart, bsum);
    fill_k <<<NBL_E, 256, 0, stream>>>(ei, ea, dinv, colstart, poff, rankpack, epack);

    gemm128<float><<<NTILE, 256, 0, stream>>>(x, Wt1, h, M_TOT);
    gather2_k<false><<<NBL_G, 256, 0, stream>>>(h, epack, colstart, cnt, dinv, b1, o1);
    gemm128<u16>  <<<NTILE, 256, 0, stream>>>(o1, Wt2, h, M_TOT);
    gather2_k<true> <<<NBL_G, 256, 0, stream>>>(h, epack, colstart, cnt, dinv, b2, d_out);
}

// Round 5
// 285.091 us; speedup vs baseline: 1.7469x; 1.0042x over previous
//
#include <hip/hip_runtime.h>

// Problem constants (GNNNet_678604833376): B=2, N=50000, D=128, E=640000
#define NNODES 50000
#define NBATCH 2
#define DIM    128
#define NEDGE  640000
#define M_TOT  (NBATCH*NNODES)   // 100000 rows for the GEMM
#define NXCD   8
#define NBL_N  196               // ceil(NNODES/256)

typedef unsigned short u16;
typedef unsigned int   u32;
typedef unsigned long long u64;

typedef __attribute__((ext_vector_type(8))) short bf16x8;   // 8 bf16 = 4 VGPRs
typedef __attribute__((ext_vector_type(4))) float f32x4;

__device__ __forceinline__ float bf2f(u16 u){ return __uint_as_float(((u32)u)<<16); }
__device__ __forceinline__ u16 f2bf(float f){
    u32 x = __float_as_uint(f);
    x += 0x7fffu + ((x>>16)&1u);   // round-to-nearest-even
    return (u16)(x>>16);
}

// ---------- histogram: per-XCD partials, L2-resident workgroup-scope atomics ----------
// part[xcc][c] accumulates (fixed24(ea) << 32) | 1.  All updates to partition
// xcc come from waves physically on XCD xcc, so L2-point atomicity suffices.
// Returned old value = this edge's rank in its (partition, column) bucket.
__global__ __launch_bounds__(256) void count_k(const int* __restrict__ ei,
                                               const float* __restrict__ ea,
                                               u64* __restrict__ part,
                                               u32* __restrict__ rankpack){
    u32 xcc = __builtin_amdgcn_s_getreg(6164) & 7u;   // HW_REG_XCC_ID
    int e = blockIdx.x*256 + threadIdx.x;
    if (e < NEDGE){
        int c = ei[NEDGE + e];
        u64 inc = (((u64)__float2uint_rn(ea[e] * 16777216.0f)) << 32) | 1ull;
        u64 old = __hip_atomic_fetch_add(&part[(size_t)xcc*NNODES + c], inc,
                                         __ATOMIC_RELAXED, __HIP_MEMORY_SCOPE_WORKGROUP);
        rankpack[e] = ((u32)old & 0xffffu) | (xcc << 16);
    }
}

// ---------- fused reduce + block-scan ----------
__global__ __launch_bounds__(256) void scan1(const u64* __restrict__ part,
                                             int* __restrict__ cnt,
                                             int* __restrict__ poff,
                                             float* __restrict__ dinv,
                                             int* colstart, int* bsum){
    __shared__ int s[256];
    int tid = threadIdx.x;
    int n = blockIdx.x*256 + tid;
    int v = 0;
    if (n < NNODES){
        int run = 0; u64 fsum = 0;
        #pragma unroll
        for (int p = 0; p < NXCD; ++p){
            u64 pv = part[(size_t)p*NNODES + n];
            poff[p*NNODES + n] = run;
            run  += (int)(pv & 0xffffffffu);
            fsum += (pv >> 32);
        }
        cnt[n] = run;
        v = run;
        float deg = 1.0f + (float)fsum * (1.0f/16777216.0f);   // deg >= 1
        dinv[n] = rsqrtf(deg);
    }
    s[tid] = v; __syncthreads();
    #pragma unroll
    for (int off = 1; off < 256; off <<= 1){
        int t = (tid >= off) ? s[tid-off] : 0;
        __syncthreads();
        s[tid] += t;
        __syncthreads();
    }
    if (n < NNODES) colstart[n] = s[tid] - v;     // exclusive within block
    if (tid == 255) bsum[blockIdx.x] = s[255];
}

// merged scan2+scan3: every block redundantly scans the 196 block sums,
// picks its own exclusive prefix, adds to its colstart slice.
__global__ __launch_bounds__(256) void scan23(int* colstart, const int* __restrict__ bsum){
    __shared__ int s[256];
    int tid = threadIdx.x;
    int v = (tid < NBL_N) ? bsum[tid] : 0;
    s[tid] = v; __syncthreads();
    #pragma unroll
    for (int off = 1; off < 256; off <<= 1){
        int t = (tid >= off) ? s[tid-off] : 0;
        __syncthreads();
        s[tid] += t;
        __syncthreads();
    }
    int add = s[blockIdx.x] - bsum[blockIdx.x];   // exclusive prefix for this block
    int i = blockIdx.x*256 + tid;
    if (i < NNODES) colstart[i] += add;
}

// ---------- CSR bucket fill (no atomic: pos from colstart + poff + rank) ----------
__global__ __launch_bounds__(256) void fill_k(const int* __restrict__ ei,
                                              const float* __restrict__ ea,
                                              const float* __restrict__ dinv,
                                              const int* __restrict__ colstart,
                                              const int* __restrict__ poff,
                                              const u32* __restrict__ rankpack,
                                              int2* __restrict__ epack){
    int e = blockIdx.x*256 + threadIdx.x;
    if (e < NEDGE){
        int r = ei[e], c = ei[NEDGE + e];
        u32 rp = rankpack[e];
        int pos = colstart[c] + poff[(rp >> 16)*NNODES + c] + (int)(rp & 0xffffu);
        epack[pos] = make_int2(r, __float_as_int(dinv[r] * ea[e] * dinv[c]));
    }
}

// transpose both W (fp32) -> Wt (bf16), Wt[n][k] = W[k][n]. 128 blocks.
__global__ __launch_bounds__(256) void transposeW(const float* __restrict__ W1, u16* __restrict__ Wt1,
                                                  const float* __restrict__ W2, u16* __restrict__ Wt2){
    int i = blockIdx.x*256 + threadIdx.x;
    const float* W = (i < 16384) ? W1 : W2;
    u16* Wt       = (i < 16384) ? Wt1 : Wt2;
    int ii = i & 16383;
    int k = ii >> 7, n = ii & 127;
    Wt[n*DIM + k] = f2bf(W[ii]);
}

// ---------- GEMM: H[M,128](bf16) = A[M,128](AT->bf16) @ W[128,128] ----------
__device__ __forceinline__ bf16x8 load_frag(const float* A, size_t off){
    const float4* ap = (const float4*)(A + off);
    float4 lo = ap[0], hi = ap[1];
    bf16x8 r;
    r[0] = (short)f2bf(lo.x); r[1] = (short)f2bf(lo.y);
    r[2] = (short)f2bf(lo.z); r[3] = (short)f2bf(lo.w);
    r[4] = (short)f2bf(hi.x); r[5] = (short)f2bf(hi.y);
    r[6] = (short)f2bf(hi.z); r[7] = (short)f2bf(hi.w);
    return r;
}
__device__ __forceinline__ bf16x8 load_frag(const u16* A, size_t off){
    return *(const bf16x8*)(A + off);
}

template <typename AT>
__global__ __launch_bounds__(256) void gemm128(const AT* __restrict__ A,
                                               const u16* __restrict__ Wt,
                                               u16* __restrict__ H, int M){
    __shared__ u16 Wl[128][136];   // +8 pad keeps 16B alignment, breaks 128-stride
    int tid = threadIdx.x;
    {
        const uint4* src = (const uint4*)Wt;   // 2048 x 16B
        #pragma unroll
        for (int j = 0; j < 8; ++j){
            int g = tid + j*256;
            int n = g >> 4;
            int k = (g & 15) * 8;
            *(uint4*)&Wl[n][k] = src[g];
        }
    }
    __syncthreads();

    int wave = tid >> 6, lane = tid & 63;
    int quad = lane >> 4, r = lane & 15;
    int row0 = blockIdx.x*256 + wave*64;

    f32x4 acc[4][8];
    #pragma unroll
    for (int mt = 0; mt < 4; ++mt)
        #pragma unroll
        for (int nt = 0; nt < 8; ++nt)
            acc[mt][nt] = (f32x4){0.f,0.f,0.f,0.f};

    #pragma unroll
    for (int ks = 0; ks < 4; ++ks){
        bf16x8 af[4];
        #pragma unroll
        for (int mt = 0; mt < 4; ++mt){
            int row = row0 + mt*16 + r;
            if (row < M)
                af[mt] = load_frag(A, (size_t)row*DIM + ks*32 + quad*8);
            else
                af[mt] = (bf16x8){0,0,0,0,0,0,0,0};
        }
        #pragma unroll
        for (int nt = 0; nt < 8; ++nt){
            bf16x8 bfr = *(const bf16x8*)&Wl[nt*16 + r][ks*32 + quad*8];
            #pragma unroll
            for (int mt = 0; mt < 4; ++mt)
                acc[mt][nt] = __builtin_amdgcn_mfma_f32_16x16x32_bf16(af[mt], bfr, acc[mt][nt], 0, 0, 0);
        }
    }

    // C/D layout: col = lane&15 (=r), row = quad*4 + reg
    #pragma unroll
    for (int mt = 0; mt < 4; ++mt){
        #pragma unroll
        for (int reg = 0; reg < 4; ++reg){
            int row = row0 + mt*16 + quad*4 + reg;
            if (row < M){
                #pragma unroll
                for (int nt = 0; nt < 8; ++nt)
                    H[(size_t)row*DIM + nt*16 + r] = f2bf(acc[mt][nt][reg]);
            }
        }
    }
}

// ---------- gather-aggregate: one wave = one (node, batch) ----------
// batch = blockIdx.x & 1 -> under bid%8 XCD round-robin, even XCDs touch only
// H-batch0, odd only H-batch1 (12.8 MB working set per XCD instead of 25.6).
// 8 row-loads in flight per wave; tail padded with row 0 / weight 0.
#define EFMA(W_, V_)                                        \
    a0 = fmaf(W_, bf2f((u16)((V_) & 0xffff)), a0);          \
    a1 = fmaf(W_, bf2f((u16)((V_) >> 16)),    a1);

template <bool OUT_F32>
__global__ __launch_bounds__(256) void gather1b_k(const u16* __restrict__ H,
                                                  const int2* __restrict__ epack,
                                                  const int* __restrict__ colstart,
                                                  const int* __restrict__ cnt,
                                                  const float* __restrict__ dinv,
                                                  const float* __restrict__ bias,
                                                  void* __restrict__ out){
    int wave = threadIdx.x >> 6, lane = threadIdx.x & 63;
    int bid = blockIdx.x;
    int batch = bid & 1;
    int n = (bid >> 1)*4 + wave;
    if (n >= NNODES) return;
    const u32* Hb = (const u32*)H + (size_t)batch*NNODES*64;   // 64 u32 per row

    float dn = dinv[n], dn2 = dn*dn;
    u32 sv = Hb[(size_t)n*64 + lane];
    float a0 = dn2*bf2f((u16)(sv & 0xffff));
    float a1 = dn2*bf2f((u16)(sv >> 16));

    int s = colstart[n], c = cnt[n];
    for (int base = 0; base < c; base += 64){
        int m = min(64, c - base);
        int2 ep = make_int2(0, 0);                 // row 0, weight 0.0f pad
        if (lane < m) ep = epack[s + base + lane];
        for (int j = 0; j < m; j += 8){
            int r0 = __shfl(ep.x, j+0), r1 = __shfl(ep.x, j+1);
            int r2 = __shfl(ep.x, j+2), r3 = __shfl(ep.x, j+3);
            int r4 = __shfl(ep.x, j+4), r5 = __shfl(ep.x, j+5);
            int r6 = __shfl(ep.x, j+6), r7 = __shfl(ep.x, j+7);
            float w0 = __int_as_float(__shfl(ep.y, j+0));
            float w1 = __int_as_float(__shfl(ep.y, j+1));
            float w2 = __int_as_float(__shfl(ep.y, j+2));
            float w3 = __int_as_float(__shfl(ep.y, j+3));
            float w4 = __int_as_float(__shfl(ep.y, j+4));
            float w5 = __int_as_float(__shfl(ep.y, j+5));
            float w6 = __int_as_float(__shfl(ep.y, j+6));
            float w7 = __int_as_float(__shfl(ep.y, j+7));
            u32 v0 = Hb[(size_t)r0*64 + lane];
            u32 v1 = Hb[(size_t)r1*64 + lane];
            u32 v2 = Hb[(size_t)r2*64 + lane];
            u32 v3 = Hb[(size_t)r3*64 + lane];
            u32 v4 = Hb[(size_t)r4*64 + lane];
            u32 v5 = Hb[(size_t)r5*64 + lane];
            u32 v6 = Hb[(size_t)r6*64 + lane];
            u32 v7 = Hb[(size_t)r7*64 + lane];
            EFMA(w0, v0) EFMA(w1, v1) EFMA(w2, v2) EFMA(w3, v3)
            EFMA(w4, v4) EFMA(w5, v5) EFMA(w6, v6) EFMA(w7, v7)
        }
    }
    a0 = fmaxf(a0 + bias[lane*2    ], 0.f);
    a1 = fmaxf(a1 + bias[lane*2 + 1], 0.f);
    if (OUT_F32){
        float2* O = (float2*)out;
        O[(size_t)(batch*NNODES + n)*64 + lane] = make_float2(a0, a1);
    } else {
        u32* O = (u32*)out;
        O[(size_t)(batch*NNODES + n)*64 + lane] = (u32)f2bf(a0) | ((u32)f2bf(a1) << 16);
    }
}

// ---------- launch ----------
extern "C" void kernel_launch(void* const* d_in, const int* in_sizes, int n_in,
                              void* d_out, int out_size, void* d_ws, size_t ws_size,
                              hipStream_t stream){
    const float* x  = (const float*)d_in[0];
    const int*   ei = (const int*)  d_in[1];
    const float* ea = (const float*)d_in[2];
    const float* W1 = (const float*)d_in[3];
    const float* b1 = (const float*)d_in[4];
    const float* W2 = (const float*)d_in[5];
    const float* b2 = (const float*)d_in[6];

    char* p = (char*)d_ws;
    auto alloc = [&](size_t bytes)->char*{ char* r = p; p += (bytes + 511) & ~(size_t)511; return r; };
    u64*   part     = (u64*)  alloc((size_t)NXCD*NNODES*8);   // 3.2 MB partial histograms
    u32*   rankpack = (u32*)  alloc((size_t)NEDGE*4);
    int*   poff     = (int*)  alloc((size_t)NXCD*NNODES*4);
    float* dinv     = (float*)alloc(NNODES*4);
    int*   cnt      = (int*)  alloc(NNODES*4);
    int*   colstart = (int*)  alloc(NNODES*4);
    int*   bsum     = (int*)  alloc(1024);
    int2*  epack    = (int2*) alloc((size_t)NEDGE*8);
    u16*   Wt1      = (u16*)  alloc(DIM*DIM*2);
    u16*   Wt2      = (u16*)  alloc(DIM*DIM*2);
    u16*   h        = (u16*)  alloc((size_t)M_TOT*DIM*2);   // bf16 intermediates
    u16*   o1       = (u16*)  alloc((size_t)M_TOT*DIM*2);   // bf16 activations

    const int NBL_E = (NEDGE  + 255)/256;
    const int NTILE = (M_TOT + 255)/256;    // 391
    const int NBL_G = 2*((NNODES + 3)/4);   // 25000 (node-quad x batch)

    hipMemsetAsync(part, 0, (size_t)NXCD*NNODES*8, stream);
    transposeW<<<128, 256, 0, stream>>>(W1, Wt1, W2, Wt2);
    count_k<<<NBL_E, 256, 0, stream>>>(ei, ea, part, rankpack);
    scan1  <<<NBL_N, 256, 0, stream>>>(part, cnt, poff, dinv, colstart, bsum);
    scan23 <<<NBL_N, 256, 0, stream>>>(colstart, bsum);
    fill_k <<<NBL_E, 256, 0, stream>>>(ei, ea, dinv, colstart, poff, rankpack, epack);

    gemm128<float><<<NTILE, 256, 0, stream>>>(x, Wt1, h, M_TOT);
    gather1b_k<false><<<NBL_G, 256, 0, stream>>>(h, epack, colstart, cnt, dinv, b1, o1);
    gemm128<u16>  <<<NTILE, 256, 0, stream>>>(o1, Wt2, h, M_TOT);
    gather1b_k<true> <<<NBL_G, 256, 0, stream>>>(h, epack, colstart, cnt, dinv, b2, d_out);
}